// Round 1
// baseline (574.418 us; speedup 1.0000x reference)
//
#include <hip/hip_runtime.h>
#include <cmath>

#define NT_A 128
#define B_ROWS 32768
#define N_LEN 1116

// db4 decomposition filters (reconstruction taps fold to these after double reversal)
constexpr float D_LO[8] = {-0.010597401784997278f, 0.032883011666982945f,
                           0.030841381835986965f, -0.18703481171888114f,
                           -0.02798376941698385f, 0.6308807679295904f,
                           0.7148465705525415f,   0.23037781330885523f};
constexpr float D_HI[8] = {-0.23037781330885523f, 0.7148465705525415f,
                           -0.6308807679295904f,  -0.02798376941698385f,
                           0.18703481171888114f,  0.030841381835986965f,
                           -0.032883011666982945f, -0.010597401784997278f};

__device__ __forceinline__ float softf(float c, float t) {
  return copysignf(fmaxf(fabsf(c) - t, 0.0f), c);
}

// a[i] = sum_k LO[k]*x[2i+1-k], d[i] = soft(sum_k HI[k]*x[2i+1-k])
__device__ __forceinline__ void dwt_level(const float* __restrict__ in, int n,
                                          float* __restrict__ A, float* __restrict__ D,
                                          int m, float t, int tid) {
  for (int i = tid; i < m; i += NT_A) {
    float sa = 0.f, sd = 0.f;
    int j0 = 2 * i + 1;
#pragma unroll
    for (int k = 0; k < 8; k++) {
      int j = j0 - k;
      float xv = (j >= 0 && j < n) ? in[j] : 0.f;
      sa = fmaf(D_LO[k], xv, sa);
      sd = fmaf(D_HI[k], xv, sd);
    }
    A[i] = sa;
    D[i] = softf(sd, t);
  }
}

// y[o] = sum_i a[i]*LO[2i+1-o] + d[i]*HI[2i+1-o]; 4 taps from i0=o>>1
__device__ __forceinline__ void idwt_level(const float* __restrict__ A,
                                           const float* __restrict__ D, int m,
                                           float* __restrict__ Y, int outLen, int tid) {
  for (int o = tid; o < outLen; o += NT_A) {
    int i0 = o >> 1;
    float s = 0.f;
    if (o & 1) {
#pragma unroll
      for (int t2 = 0; t2 < 4; t2++) {
        int i = i0 + t2;
        if (i < m) { s = fmaf(A[i], D_LO[2 * t2], s); s = fmaf(D[i], D_HI[2 * t2], s); }
      }
    } else {
#pragma unroll
      for (int t2 = 0; t2 < 4; t2++) {
        int i = i0 + t2;
        if (i < m) { s = fmaf(A[i], D_LO[2 * t2 + 1], s); s = fmaf(D[i], D_HI[2 * t2 + 1], s); }
      }
    }
    Y[o] = s;
  }
}

__global__ __launch_bounds__(NT_A) void wavelet_kernel(const float* __restrict__ x,
                                                       const float* __restrict__ thr,
                                                       float* __restrict__ out) {
  // LDS layout (floats): X 1116 | P 561 | Q 284 | D1 561 | D2 284 | D3 145 | D4 76 | D5 41 | D6 24 | D7 15
  __shared__ __align__(16) float lds[3107];
  float* X  = lds;
  float* P  = lds + 1116;
  float* Q  = lds + 1677;
  float* D1 = lds + 1961;
  float* D2 = lds + 2522;
  float* D3 = lds + 2806;
  float* D4 = lds + 2951;
  float* D5 = lds + 3027;
  float* D6 = lds + 3068;
  float* D7 = lds + 3092;

  const int tid = threadIdx.x;
  const long long row = blockIdx.x;
  const float t = fmaxf(thr[0], 0.01f);

  const float4* xr = (const float4*)(x + row * N_LEN);
  for (int i = tid; i < N_LEN / 4; i += NT_A) ((float4*)X)[i] = xr[i];
  __syncthreads();

  dwt_level(X, 1116, P, D1, 561, t, tid); __syncthreads();
  dwt_level(P, 561,  Q, D2, 284, t, tid); __syncthreads();
  dwt_level(Q, 284,  P, D3, 145, t, tid); __syncthreads();
  dwt_level(P, 145,  Q, D4, 76,  t, tid); __syncthreads();
  dwt_level(Q, 76,   P, D5, 41,  t, tid); __syncthreads();
  dwt_level(P, 41,   Q, D6, 24,  t, tid); __syncthreads();
  dwt_level(Q, 24,   P, D7, 15,  t, tid); __syncthreads();

  for (int i = tid; i < 15; i += NT_A) P[i] = softf(P[i], t);
  __syncthreads();

  // reconstruction; output lengths pre-trimmed (a[:-1] drops are never computed)
  idwt_level(P, D7, 15,  Q, 24,   tid); __syncthreads();
  idwt_level(Q, D6, 24,  P, 41,   tid); __syncthreads();  // full 42, keep 41
  idwt_level(P, D5, 41,  Q, 76,   tid); __syncthreads();
  idwt_level(Q, D4, 76,  P, 145,  tid); __syncthreads();  // full 146, keep 145
  idwt_level(P, D3, 145, Q, 284,  tid); __syncthreads();
  idwt_level(Q, D2, 284, P, 561,  tid); __syncthreads();  // full 562, keep 561
  idwt_level(P, D1, 561, X, 1116, tid); __syncthreads();

  float4* orow = (float4*)(out + row * N_LEN);
  for (int i = tid; i < N_LEN / 4; i += NT_A) orow[i] = ((const float4*)X)[i];
}

// reg head: h = sigmoid(recon @ W1^T + b1); reg = h @ W2^T + b2.
// 64 rows x 100 cols per block; 256 threads = 4 col-groups(25 cols) x 64 lanes(rows).
__global__ __launch_bounds__(256) void head_kernel(const float* __restrict__ recon,
                                                   const float* __restrict__ W1,
                                                   const float* __restrict__ b1,
                                                   const float* __restrict__ W2,
                                                   const float* __restrict__ b2,
                                                   float* __restrict__ reg_out) {
  __shared__ __align__(16) float Wt[100][16];  // [col][kk]
  __shared__ __align__(16) float R[64][20];    // [row][kk], stride 20 for bank spread
  __shared__ float preg[4][64];

  const int tid  = threadIdx.x;
  const int lane = tid & 63;   // row within tile
  const int colg = tid >> 6;   // 0..3
  const int cbase = colg * 25;
  const long long row0 = (long long)blockIdx.x * 64;

  float acc[25];
#pragma unroll
  for (int c = 0; c < 25; c++) acc[c] = 0.f;

  for (int kt = 0; kt < 70; kt++) {
    const int k0 = kt * 16;
    // stage W1 tile: 100x16
    for (int idx = tid; idx < 400; idx += 256) {
      int c = idx >> 2, q = idx & 3;
      int k = k0 + q * 4;
      float4 v = make_float4(0.f, 0.f, 0.f, 0.f);
      if (k + 3 < N_LEN) v = *(const float4*)(W1 + (long long)c * N_LEN + k);
      *(float4*)&Wt[c][q * 4] = v;
    }
    // stage recon tile: 64x16
    {
      int m = tid >> 2, q = tid & 3;
      int k = k0 + q * 4;
      float4 v = make_float4(0.f, 0.f, 0.f, 0.f);
      if (k + 3 < N_LEN) v = *(const float4*)(recon + (row0 + m) * N_LEN + k);
      *(float4*)&R[m][q * 4] = v;
    }
    __syncthreads();
#pragma unroll
    for (int q = 0; q < 4; q++) {
      float4 r = *(const float4*)&R[lane][q * 4];
#pragma unroll
      for (int c = 0; c < 25; c++) {
        float4 w = *(const float4*)&Wt[cbase + c][q * 4];
        acc[c] = fmaf(r.x, w.x, acc[c]);
        acc[c] = fmaf(r.y, w.y, acc[c]);
        acc[c] = fmaf(r.z, w.z, acc[c]);
        acc[c] = fmaf(r.w, w.w, acc[c]);
      }
    }
    __syncthreads();
  }

  float p = 0.f;
#pragma unroll
  for (int c = 0; c < 25; c++) {
    float z = acc[c] + b1[cbase + c];
    float h = 1.f / (1.f + expf(-z));
    p = fmaf(h, W2[cbase + c], p);
  }
  preg[colg][lane] = p;
  __syncthreads();
  if (colg == 0) {
    float r = preg[0][lane] + preg[1][lane] + preg[2][lane] + preg[3][lane] + b2[0];
    reg_out[row0 + lane] = r;
  }
}

extern "C" void kernel_launch(void* const* d_in, const int* in_sizes, int n_in,
                              void* d_out, int out_size, void* d_ws, size_t ws_size,
                              hipStream_t stream) {
  const float* x   = (const float*)d_in[0];
  const float* thr = (const float*)d_in[1];
  const float* W1  = (const float*)d_in[2];
  const float* b1  = (const float*)d_in[3];
  const float* W2  = (const float*)d_in[4];
  const float* b2  = (const float*)d_in[5];
  float* out = (float*)d_out;
  float* reg_out = out + (long long)B_ROWS * N_LEN;

  hipLaunchKernelGGL(wavelet_kernel, dim3(B_ROWS), dim3(NT_A), 0, stream, x, thr, out);
  hipLaunchKernelGGL(head_kernel, dim3(B_ROWS / 64), dim3(256), 0, stream,
                     out, W1, b1, W2, b2, reg_out);
}

// Round 2
// 413.095 us; speedup vs baseline: 1.3905x; 1.3905x over previous
//
#include <hip/hip_runtime.h>
#include <cmath>

typedef __attribute__((ext_vector_type(4))) float f32x4;
typedef __attribute__((ext_vector_type(8))) short s16x8;

#define B_ROWS 32768
#define N_LEN 1116

// db4 decomposition filters (reconstruction taps fold back to these)
__device__ constexpr float D_LO[8] = {-0.010597401784997278f, 0.032883011666982945f,
                                      0.030841381835986965f, -0.18703481171888114f,
                                      -0.02798376941698385f, 0.6308807679295904f,
                                      0.7148465705525415f,   0.23037781330885523f};
__device__ constexpr float D_HI[8] = {-0.23037781330885523f, 0.7148465705525415f,
                                      -0.6308807679295904f,  -0.02798376941698385f,
                                      0.18703481171888114f,  0.030841381835986965f,
                                      -0.032883011666982945f, -0.010597401784997278f};

__device__ __forceinline__ float softf(float c, float t) {
  return copysignf(fmaxf(fabsf(c) - t, 0.0f), c);
}

// ---------------- wavelet kernel: 1 wave per row, wave-synchronous ----------------
// Per-row LDS layout (floats), every buffer has 8-front pad; ptr points at elem 0.
#define WV_STRIDE 3268
#define OX  8
#define OP  1140
#define OQ  1717
#define OD1 2017
#define OD2 2594
#define OD3 2894
#define OD4 3055
#define OD5 3147
#define OD6 3204
#define OD7 3244

// a[i] = sum_k LO[k]*in[2i+1-k]; d[i] = soft(sum_k HI[k]*in[2i+1-k])
// pads: in[-8..0) and in[n..n+8) are zero (producer guarantees)
__device__ __forceinline__ void dwt_level(const float* in, float* A, float* D,
                                          const int m, const float t, const int lane) {
  for (int i = lane; i < m; i += 64) {
    const float* p = in + 2 * i - 6;  // p[7-k] = in[2i+1-k]
    float sa = 0.f, sd = 0.f;
#pragma unroll
    for (int k = 0; k < 8; k++) {
      float xv = p[7 - k];
      sa = fmaf(D_LO[k], xv, sa);
      sd = fmaf(D_HI[k], xv, sd);
    }
    A[i] = sa;
    D[i] = softf(sd, t);
  }
  if (lane < 8) { A[m + lane] = 0.f; D[m + lane] = 0.f; }  // back pad for next dwt
}

// y[2u]   = sum_t A[u+t]*LO[2t+1] + D[u+t]*HI[2t+1]
// y[2u+1] = sum_t A[u+t]*LO[2t]   + D[u+t]*HI[2t]
__device__ __forceinline__ void idwt_level(const float* A, const float* D,
                                           float* Y, const int outLen, const int lane) {
  const int half = (outLen + 1) >> 1;
  for (int u = lane; u < half; u += 64) {
    float a0 = A[u], a1 = A[u + 1], a2 = A[u + 2], a3 = A[u + 3];
    float d0 = D[u], d1 = D[u + 1], d2 = D[u + 2], d3 = D[u + 3];
    float ye = a0 * D_LO[1];
    ye = fmaf(a1, D_LO[3], ye); ye = fmaf(a2, D_LO[5], ye); ye = fmaf(a3, D_LO[7], ye);
    ye = fmaf(d0, D_HI[1], ye); ye = fmaf(d1, D_HI[3], ye);
    ye = fmaf(d2, D_HI[5], ye); ye = fmaf(d3, D_HI[7], ye);
    float yo = a0 * D_LO[0];
    yo = fmaf(a1, D_LO[2], yo); yo = fmaf(a2, D_LO[4], yo); yo = fmaf(a3, D_LO[6], yo);
    yo = fmaf(d0, D_HI[0], yo); yo = fmaf(d1, D_HI[2], yo);
    yo = fmaf(d2, D_HI[4], yo); yo = fmaf(d3, D_HI[6], yo);
    Y[2 * u] = ye;
    if (2 * u + 1 < outLen) Y[2 * u + 1] = yo;
  }
  if (lane < 8) Y[outLen + lane] = 0.f;  // back pad for next dwt consumer
}

__global__ __launch_bounds__(256) void wavelet_kernel(const float* __restrict__ x,
                                                      const float* __restrict__ thr,
                                                      float* __restrict__ out) {
  __shared__ float lds[4 * WV_STRIDE];  // 52.3 KB, 3 blocks/CU
  const int lane = threadIdx.x & 63;
  const int wave = threadIdx.x >> 6;
  const long long row = (long long)blockIdx.x * 4 + wave;
  float* base = lds + wave * WV_STRIDE;
  float* X  = base + OX;
  float* P  = base + OP;
  float* Q  = base + OQ;
  float* D1 = base + OD1;
  float* D2 = base + OD2;
  float* D3 = base + OD3;
  float* D4 = base + OD4;
  float* D5 = base + OD5;
  float* D6 = base + OD6;
  float* D7 = base + OD7;

  const float t = fmaxf(thr[0], 0.01f);

  // zero all front pads + X back pad (never written elsewhere)
  if (lane < 8) {
    X[lane - 8] = 0.f; P[lane - 8] = 0.f; Q[lane - 8] = 0.f;
    D1[lane - 8] = 0.f; D2[lane - 8] = 0.f; D3[lane - 8] = 0.f; D4[lane - 8] = 0.f;
    D5[lane - 8] = 0.f; D6[lane - 8] = 0.f; D7[lane - 8] = 0.f;
    X[1116 + lane] = 0.f;
  }
  // stage input row (float4)
  {
    const float4* xr = (const float4*)(x + row * N_LEN);
    float4* X4 = (float4*)X;
    for (int i = lane; i < N_LEN / 4; i += 64) X4[i] = xr[i];
  }

  // decomposition: X(1116)->P(561)->Q(284)->P(145)->Q(76)->P(41)->Q(24)->P(15)
  dwt_level(X, P, D1, 561, t, lane);
  dwt_level(P, Q, D2, 284, t, lane);
  dwt_level(Q, P, D3, 145, t, lane);
  dwt_level(P, Q, D4, 76,  t, lane);
  dwt_level(Q, P, D5, 41,  t, lane);
  dwt_level(P, Q, D6, 24,  t, lane);
  dwt_level(Q, P, D7, 15,  t, lane);

  if (lane < 15) P[lane] = softf(P[lane], t);

  // reconstruction (trimmed lengths computed directly)
  idwt_level(P, D7, Q, 24,   lane);
  idwt_level(Q, D6, P, 41,   lane);
  idwt_level(P, D5, Q, 76,   lane);
  idwt_level(Q, D4, P, 145,  lane);
  idwt_level(P, D3, Q, 284,  lane);
  idwt_level(Q, D2, P, 561,  lane);
  idwt_level(P, D1, X, 1116, lane);

  float4* orow = (float4*)(out + row * N_LEN);
  const float4* X4 = (const float4*)X;
  for (int i = lane; i < N_LEN / 4; i += 64) orow[i] = X4[i];
}

// ---------------- head: bf16 MFMA GEMM + fused sigmoid/W2 reduce ----------------
__device__ __forceinline__ short f2bf(float f) {
  unsigned u = __float_as_uint(f);
  unsigned r = (u + 0x7FFFu + ((u >> 16) & 1u)) >> 16;  // RNE
  return (short)r;
}
__device__ __forceinline__ s16x8 cvt8(float4 a, float4 b) {
  s16x8 v;
  v[0] = f2bf(a.x); v[1] = f2bf(a.y); v[2] = f2bf(a.z); v[3] = f2bf(a.w);
  v[4] = f2bf(b.x); v[5] = f2bf(b.y); v[6] = f2bf(b.z); v[7] = f2bf(b.w);
  return v;
}

// Z[m][n] = sum_k recon[m][k]*W1[n][k]; h=sigmoid(Z+b1); reg = h@W2^T + b2
// wave computes 16 rows x 112 cols (7 col-tiles of 16; cols>=100 masked)
__global__ __launch_bounds__(256) void head_mfma(const float* __restrict__ recon,
                                                 const float* __restrict__ W1,
                                                 const float* __restrict__ b1,
                                                 const float* __restrict__ W2,
                                                 const float* __restrict__ b2,
                                                 float* __restrict__ reg_out) {
  const int lane = threadIdx.x & 63;
  const int wave = threadIdx.x >> 6;
  const int m0 = (blockIdx.x * 4 + wave) * 16;
  const int r16 = lane & 15;           // A-row / B-col within tile
  const int kg = (lane >> 4) * 8;      // k-offset within 32-chunk
  const float* arow = recon + (long long)(m0 + r16) * N_LEN;

  f32x4 acc[7];
#pragma unroll
  for (int c = 0; c < 7; c++) acc[c] = (f32x4){0.f, 0.f, 0.f, 0.f};

  for (int ks = 0; ks < 34; ks++) {  // 34 full k-steps of 32 (k<1088)
    const int k0 = ks * 32 + kg;
    float4 a0 = *(const float4*)(arow + k0);
    float4 a1 = *(const float4*)(arow + k0 + 4);
    s16x8 av = cvt8(a0, a1);
#pragma unroll
    for (int ct = 0; ct < 7; ct++) {
      const int col = ct * 16 + r16;
      s16x8 bv = (s16x8)(short)0;
      if (col < 100) {
        const float* wrow = W1 + (long long)col * N_LEN + k0;
        bv = cvt8(*(const float4*)wrow, *(const float4*)(wrow + 4));
      }
      acc[ct] = __builtin_amdgcn_mfma_f32_16x16x32_bf16(av, bv, acc[ct], 0, 0, 0);
    }
  }
  {  // tail k-step: k = 1088..1115 (28 valid of 32)
    const int k0 = 1088 + kg;
    float af[8];
#pragma unroll
    for (int e = 0; e < 8; e++) af[e] = (k0 + e < N_LEN) ? arow[k0 + e] : 0.f;
    s16x8 av;
#pragma unroll
    for (int e = 0; e < 8; e++) av[e] = f2bf(af[e]);
#pragma unroll
    for (int ct = 0; ct < 7; ct++) {
      const int col = ct * 16 + r16;
      s16x8 bv = (s16x8)(short)0;
      if (col < 100) {
        const float* wrow = W1 + (long long)col * N_LEN;
#pragma unroll
        for (int e = 0; e < 8; e++) bv[e] = f2bf((k0 + e < N_LEN) ? wrow[k0 + e] : 0.f);
      }
      acc[ct] = __builtin_amdgcn_mfma_f32_16x16x32_bf16(av, bv, acc[ct], 0, 0, 0);
    }
  }

  // epilogue: lane holds Z[(lane>>4)*4 + r][ct*16 + r16]
  float psum[4] = {0.f, 0.f, 0.f, 0.f};
#pragma unroll
  for (int ct = 0; ct < 7; ct++) {
    const int col = ct * 16 + r16;
    if (col < 100) {
      const float b1v = b1[col];
      const float w2v = W2[col];
#pragma unroll
      for (int r = 0; r < 4; r++) {
        float z = acc[ct][r] + b1v;
        float h = 1.f / (1.f + expf(-z));
        psum[r] = fmaf(h, w2v, psum[r]);
      }
    }
  }
#pragma unroll
  for (int mask = 1; mask < 16; mask <<= 1) {
#pragma unroll
    for (int r = 0; r < 4; r++) psum[r] += __shfl_xor(psum[r], mask, 64);
  }
  if (r16 == 0) {
    const float b2v = b2[0];
#pragma unroll
    for (int r = 0; r < 4; r++) reg_out[m0 + (lane >> 4) * 4 + r] = psum[r] + b2v;
  }
}

extern "C" void kernel_launch(void* const* d_in, const int* in_sizes, int n_in,
                              void* d_out, int out_size, void* d_ws, size_t ws_size,
                              hipStream_t stream) {
  const float* x   = (const float*)d_in[0];
  const float* thr = (const float*)d_in[1];
  const float* W1  = (const float*)d_in[2];
  const float* b1  = (const float*)d_in[3];
  const float* W2  = (const float*)d_in[4];
  const float* b2  = (const float*)d_in[5];
  float* out = (float*)d_out;
  float* reg_out = out + (long long)B_ROWS * N_LEN;

  hipLaunchKernelGGL(wavelet_kernel, dim3(B_ROWS / 4), dim3(256), 0, stream, x, thr, out);
  hipLaunchKernelGGL(head_mfma, dim3(B_ROWS / 64), dim3(256), 0, stream,
                     out, W1, b1, W2, b2, reg_out);
}

// Round 4
// 341.254 us; speedup vs baseline: 1.6833x; 1.2105x over previous
//
#include <hip/hip_runtime.h>
#include <cmath>

typedef __attribute__((ext_vector_type(4))) float f32x4;
typedef __attribute__((ext_vector_type(8))) short s16x8;

#define B_ROWS 32768
#define N_LEN 1116

__device__ constexpr float D_LO[8] = {-0.010597401784997278f, 0.032883011666982945f,
                                      0.030841381835986965f, -0.18703481171888114f,
                                      -0.02798376941698385f, 0.6308807679295904f,
                                      0.7148465705525415f,   0.23037781330885523f};
__device__ constexpr float D_HI[8] = {-0.23037781330885523f, 0.7148465705525415f,
                                      -0.6308807679295904f,  -0.02798376941698385f,
                                      0.18703481171888114f,  0.030841381835986965f,
                                      -0.032883011666982945f, -0.010597401784997278f};

__device__ __forceinline__ float softf(float c, float t) {
  return copysignf(fmaxf(fabsf(c) - t, 0.0f), c);
}

// ---------------- wavelet: 1 wave/row, wave-synchronous, b128-vectorized ----------------
// LDS per-wave layout (floats); every start 4-float aligned; P,Q have 8-float front pads.
#define WV_STRIDE 2220
#define OP  8     // P: 561
#define OQ  596   // Q: 284
#define OD1 904   // 561
#define OD2 1492  // 284
#define OD3 1800  // 145
#define OD4 1972  // 76
#define OD5 2072  // 41
#define OD6 2140  // 24
#define OD7 2188  // 15

// 4 outputs (i=4u..4u+3) from window w[16] = in[8u-8 .. 8u+7]
__device__ __forceinline__ void dwt_compute_store(const float w[16], float* A, float* D,
                                                  int u, int m, float t) {
  float sa[4], sd[4];
#pragma unroll
  for (int c = 0; c < 4; c++) {
    float a = 0.f, d = 0.f;
#pragma unroll
    for (int k = 0; k < 8; k++) {
      float xv = w[2 * c + 9 - k];  // in[2(4u+c)+1-k]
      a = fmaf(D_LO[k], xv, a);
      d = fmaf(D_HI[k], xv, d);
    }
    sa[c] = a;
    sd[c] = softf(d, t);
  }
  const int i0 = 4 * u;
  float4 va, vd;
  if (i0 + 3 < m) {
    va = make_float4(sa[0], sa[1], sa[2], sa[3]);
    vd = make_float4(sd[0], sd[1], sd[2], sd[3]);
  } else {  // masked tail: keep pad region zero for downstream over-reads
    va.x = (i0 + 0 < m) ? sa[0] : 0.f; vd.x = (i0 + 0 < m) ? sd[0] : 0.f;
    va.y = (i0 + 1 < m) ? sa[1] : 0.f; vd.y = (i0 + 1 < m) ? sd[1] : 0.f;
    va.z = (i0 + 2 < m) ? sa[2] : 0.f; vd.z = (i0 + 2 < m) ? sd[2] : 0.f;
    va.w = (i0 + 3 < m) ? sa[3] : 0.f; vd.w = (i0 + 3 < m) ? sd[3] : 0.f;
  }
  *(float4*)(A + i0) = va;
  *(float4*)(D + i0) = vd;
}

__device__ __forceinline__ void dwt_zero_tail(float* A, float* D, int m, int lane) {
  const int m4 = (m + 3) & ~3;
  if (lane < 4) {
    ((float4*)(A + m4))[lane] = make_float4(0.f, 0.f, 0.f, 0.f);
    ((float4*)(D + m4))[lane] = make_float4(0.f, 0.f, 0.f, 0.f);
  }
}

__device__ __forceinline__ void dwt_lds(const float* in, float* A, float* D,
                                        int m, float t, int lane) {
  const int units = (m + 3) >> 2;
  for (int u = lane; u < units; u += 64) {
    float w[16];
    const float4* p = (const float4*)(in + 8 * u - 8);
#pragma unroll
    for (int q = 0; q < 4; q++) {
      float4 v = p[q];
      w[4 * q] = v.x; w[4 * q + 1] = v.y; w[4 * q + 2] = v.z; w[4 * q + 3] = v.w;
    }
    dwt_compute_store(w, A, D, u, m, t);
  }
  dwt_zero_tail(A, D, m, lane);
}

// 8 outputs (o=8w..8w+7) = pairs u=4w..4w+3 from A[4w..4w+6], D[4w..4w+6]
__device__ __forceinline__ void idwt_pairs(const float a[8], const float d[8], float y[8]) {
#pragma unroll
  for (int s = 0; s < 4; s++) {
    float ye = a[s] * D_LO[1];
    ye = fmaf(a[s + 1], D_LO[3], ye); ye = fmaf(a[s + 2], D_LO[5], ye);
    ye = fmaf(a[s + 3], D_LO[7], ye);
    ye = fmaf(d[s], D_HI[1], ye); ye = fmaf(d[s + 1], D_HI[3], ye);
    ye = fmaf(d[s + 2], D_HI[5], ye); ye = fmaf(d[s + 3], D_HI[7], ye);
    float yo = a[s] * D_LO[0];
    yo = fmaf(a[s + 1], D_LO[2], yo); yo = fmaf(a[s + 2], D_LO[4], yo);
    yo = fmaf(a[s + 3], D_LO[6], yo);
    yo = fmaf(d[s], D_HI[0], yo); yo = fmaf(d[s + 1], D_HI[2], yo);
    yo = fmaf(d[s + 2], D_HI[4], yo); yo = fmaf(d[s + 3], D_HI[6], yo);
    y[2 * s] = ye;
    y[2 * s + 1] = yo;
  }
}

__device__ __forceinline__ void idwt_lds(const float* A, const float* D, float* Y,
                                         int outLen, int lane) {
  const int units = (outLen + 7) >> 3;
  for (int w = lane; w < units; w += 64) {
    float a[8], d[8], y[8];
    *(float4*)&a[0] = *(const float4*)(A + 4 * w);
    *(float4*)&a[4] = *(const float4*)(A + 4 * w + 4);
    *(float4*)&d[0] = *(const float4*)(D + 4 * w);
    *(float4*)&d[4] = *(const float4*)(D + 4 * w + 4);
    idwt_pairs(a, d, y);
    const int o0 = 8 * w;
    if (o0 + 7 >= outLen) {  // masked tail (writes land in pad space)
#pragma unroll
      for (int e = 0; e < 8; e++) y[e] = (o0 + e < outLen) ? y[e] : 0.f;
    }
    *(float4*)(Y + o0) = make_float4(y[0], y[1], y[2], y[3]);
    *(float4*)(Y + o0 + 4) = make_float4(y[4], y[5], y[6], y[7]);
  }
  const int y8 = (outLen + 7) & ~7;
  if (lane < 2) ((float4*)(Y + y8))[lane] = make_float4(0.f, 0.f, 0.f, 0.f);
}

__global__ __launch_bounds__(256) void wavelet_kernel(const float* __restrict__ x,
                                                      const float* __restrict__ thr,
                                                      float* __restrict__ out) {
  __shared__ float lds[4 * WV_STRIDE];  // 35.5 KB -> 4 blocks/CU
  const int lane = threadIdx.x & 63;
  const int wave = threadIdx.x >> 6;
  const long long row = (long long)blockIdx.x * 4 + wave;
  float* base = lds + wave * WV_STRIDE;
  float* P  = base + OP;
  float* Q  = base + OQ;
  float* D1 = base + OD1;
  float* D2 = base + OD2;
  float* D3 = base + OD3;
  float* D4 = base + OD4;
  float* D5 = base + OD5;
  float* D6 = base + OD6;
  float* D7 = base + OD7;

  const float t = fmaxf(thr[0], 0.01f);
  const float* xr = x + row * N_LEN;

  // zero P,Q front pads (dwt reads in[-8..))
  if (lane < 2) {
    ((float4*)(P - 8))[lane] = make_float4(0.f, 0.f, 0.f, 0.f);
    ((float4*)(Q - 8))[lane] = make_float4(0.f, 0.f, 0.f, 0.f);
  }

  // level-1 DWT straight from global (x row is L3/L1-served; lanes overlap 50%)
  for (int u = lane; u < 141; u += 64) {
    float w[16];
    if (u >= 1 && u <= 138) {
      const float4* p = (const float4*)(xr + 8 * u - 8);
#pragma unroll
      for (int q = 0; q < 4; q++) {
        float4 v = p[q];
        w[4 * q] = v.x; w[4 * q + 1] = v.y; w[4 * q + 2] = v.z; w[4 * q + 3] = v.w;
      }
    } else {
#pragma unroll
      for (int e = 0; e < 16; e++) {
        int k = 8 * u - 8 + e;
        w[e] = (k >= 0 && k < N_LEN) ? xr[k] : 0.f;
      }
    }
    dwt_compute_store(w, P, D1, u, 561, t);
  }
  dwt_zero_tail(P, D1, 561, lane);

  dwt_lds(P, Q, D2, 284, t, lane);
  dwt_lds(Q, P, D3, 145, t, lane);
  dwt_lds(P, Q, D4, 76,  t, lane);
  dwt_lds(Q, P, D5, 41,  t, lane);
  dwt_lds(P, Q, D6, 24,  t, lane);
  dwt_lds(Q, P, D7, 15,  t, lane);

  if (lane < 15) P[lane] = softf(P[lane], t);

  idwt_lds(P, D7, Q, 24,  lane);
  idwt_lds(Q, D6, P, 41,  lane);
  idwt_lds(P, D5, Q, 76,  lane);
  idwt_lds(Q, D4, P, 145, lane);
  idwt_lds(P, D3, Q, 284, lane);
  idwt_lds(Q, D2, P, 561, lane);

  // final IDWT straight to global
  float* orow = out + row * N_LEN;
  for (int w = lane; w < 140; w += 64) {
    float a[8], d[8], y[8];
    *(float4*)&a[0] = *(const float4*)(P + 4 * w);
    *(float4*)&a[4] = *(const float4*)(P + 4 * w + 4);
    *(float4*)&d[0] = *(const float4*)(D1 + 4 * w);
    *(float4*)&d[4] = *(const float4*)(D1 + 4 * w + 4);
    idwt_pairs(a, d, y);
    const int o0 = 8 * w;
    *(float4*)(orow + o0) = make_float4(y[0], y[1], y[2], y[3]);
    if (o0 + 4 < N_LEN)  // 1116 % 8 == 4: last unit writes only first half
      *(float4*)(orow + o0 + 4) = make_float4(y[4], y[5], y[6], y[7]);
  }
}

// ---------------- head: bf16 MFMA with pre-swizzled W1 fragments ----------------
__device__ __forceinline__ short f2bf(float f) {
  unsigned u = __float_as_uint(f);
  unsigned r = (u + 0x7FFFu + ((u >> 16) & 1u)) >> 16;  // RNE
  return (short)r;
}
__device__ __forceinline__ s16x8 cvt8(float4 a, float4 b) {
  s16x8 v;
  v[0] = f2bf(a.x); v[1] = f2bf(a.y); v[2] = f2bf(a.z); v[3] = f2bf(a.w);
  v[4] = f2bf(b.x); v[5] = f2bf(b.y); v[6] = f2bf(b.z); v[7] = f2bf(b.w);
  return v;
}

#define KSTEPS 35  // ceil(1116/32)
#define NFRAG (KSTEPS * 7 * 64)

// W1 -> bf16 B-fragments: frag f=(ks,ct,lane): W1[ct*16+(lane&15)][ks*32+(lane>>4)*8 + e]
__global__ __launch_bounds__(256) void prep_w1(const float* __restrict__ W1,
                                               short* __restrict__ W1bf) {
  int f = blockIdx.x * 256 + threadIdx.x;
  if (f >= NFRAG) return;
  const int ks = f / (7 * 64);
  const int rem = f % (7 * 64);
  const int ct = rem / 64;
  const int lane = rem % 64;
  const int col = ct * 16 + (lane & 15);
  const int kbase = ks * 32 + (lane >> 4) * 8;
  s16x8 v;
#pragma unroll
  for (int e = 0; e < 8; e++) {
    const int k = kbase + e;
    float val = (col < 100 && k < N_LEN) ? W1[(long long)col * N_LEN + k] : 0.f;
    v[e] = f2bf(val);
  }
  *(s16x8*)(W1bf + (long long)f * 8) = v;
}

__global__ __launch_bounds__(256) void head_mfma(const float* __restrict__ recon,
                                                 const short* __restrict__ W1bf,
                                                 const float* __restrict__ b1,
                                                 const float* __restrict__ W2,
                                                 const float* __restrict__ b2,
                                                 float* __restrict__ reg_out) {
  const int lane = threadIdx.x & 63;
  const int wave = threadIdx.x >> 6;
  const int m0 = (blockIdx.x * 4 + wave) * 16;
  const int r16 = lane & 15;
  const int kg = (lane >> 4) * 8;
  const float* arow = recon + (long long)(m0 + r16) * N_LEN;

  f32x4 acc[7];
#pragma unroll
  for (int c = 0; c < 7; c++) acc[c] = (f32x4){0.f, 0.f, 0.f, 0.f};

  for (int ks = 0; ks < 34; ks++) {
    const int k0 = ks * 32 + kg;
    s16x8 av = cvt8(*(const float4*)(arow + k0), *(const float4*)(arow + k0 + 4));
    const s16x8* bfrag = (const s16x8*)(W1bf + ((long long)ks * 7 * 64 + lane) * 8);
#pragma unroll
    for (int ct = 0; ct < 7; ct++) {
      acc[ct] = __builtin_amdgcn_mfma_f32_16x16x32_bf16(av, bfrag[0], acc[ct], 0, 0, 0);
      bfrag += 64;  // next ct fragment block (this is the ONLY advance per ct)
    }
  }
  {  // tail ks=34 (28 valid k)
    const int k0 = 1088 + kg;
    s16x8 av;
#pragma unroll
    for (int e = 0; e < 8; e++) {
      const int k = k0 + e;
      av[e] = f2bf((k < N_LEN) ? arow[k] : 0.f);
    }
    const s16x8* bfrag = (const s16x8*)(W1bf + ((long long)34 * 7 * 64 + lane) * 8);
#pragma unroll
    for (int ct = 0; ct < 7; ct++) {
      acc[ct] = __builtin_amdgcn_mfma_f32_16x16x32_bf16(av, bfrag[0], acc[ct], 0, 0, 0);
      bfrag += 64;
    }
  }

  // epilogue: lane holds Z[(lane>>4)*4 + r][ct*16 + r16]
  float psum[4] = {0.f, 0.f, 0.f, 0.f};
#pragma unroll
  for (int ct = 0; ct < 7; ct++) {
    const int col = ct * 16 + r16;
    if (col < 100) {
      const float b1v = b1[col];
      const float w2v = W2[col];
#pragma unroll
      for (int r = 0; r < 4; r++) {
        float z = acc[ct][r] + b1v;
        float h = 1.f / (1.f + expf(-z));
        psum[r] = fmaf(h, w2v, psum[r]);
      }
    }
  }
#pragma unroll
  for (int mask = 1; mask < 16; mask <<= 1) {
#pragma unroll
    for (int r = 0; r < 4; r++) psum[r] += __shfl_xor(psum[r], mask, 64);
  }
  if (r16 == 0) {
    const float b2v = b2[0];
#pragma unroll
    for (int r = 0; r < 4; r++) reg_out[m0 + (lane >> 4) * 4 + r] = psum[r] + b2v;
  }
}

extern "C" void kernel_launch(void* const* d_in, const int* in_sizes, int n_in,
                              void* d_out, int out_size, void* d_ws, size_t ws_size,
                              hipStream_t stream) {
  const float* x   = (const float*)d_in[0];
  const float* thr = (const float*)d_in[1];
  const float* W1  = (const float*)d_in[2];
  const float* b1  = (const float*)d_in[3];
  const float* W2  = (const float*)d_in[4];
  const float* b2  = (const float*)d_in[5];
  float* out = (float*)d_out;
  float* reg_out = out + (long long)B_ROWS * N_LEN;
  short* W1bf = (short*)d_ws;  // NFRAG*8 bf16 = 250,880 B

  hipLaunchKernelGGL(prep_w1, dim3((NFRAG + 255) / 256), dim3(256), 0, stream, W1, W1bf);
  hipLaunchKernelGGL(wavelet_kernel, dim3(B_ROWS / 4), dim3(256), 0, stream, x, thr, out);
  hipLaunchKernelGGL(head_mfma, dim3(B_ROWS / 64), dim3(256), 0, stream,
                     out, W1bf, b1, W2, b2, reg_out);
}